// Round 1
// baseline (837.092 us; speedup 1.0000x reference)
//
#include <hip/hip_runtime.h>
#include <cstdint>

typedef _Float16 half8 __attribute__((ext_vector_type(8)));
typedef _Float16 half4v __attribute__((ext_vector_type(4)));
typedef float f32x4 __attribute__((ext_vector_type(4)));

__device__ __forceinline__ void async_copy16(const void* g, void* l) {
    __builtin_amdgcn_global_load_lds((const __attribute__((address_space(1))) void*)g,
                                     (__attribute__((address_space(3))) void*)l, 16, 0, 0);
}

// ---------------------------------------------------------------------------
// prep: w_s = kernel * (1/32)   [= 32 * (kernel/1024)], plus transposed copy.
// ---------------------------------------------------------------------------
__global__ __launch_bounds__(256) void prep_w(const float* __restrict__ K,
                                              _Float16* __restrict__ w0,
                                              _Float16* __restrict__ w0T) {
    __shared__ float tile[64][65];
    const int t  = threadIdx.x;
    const int bi = blockIdx.y * 64;   // in-dim block
    const int bj = blockIdx.x * 64;   // out-dim block
    const int r0 = t >> 4;            // 0..15
    const int c4 = (t & 15) * 4;      // 0..60
#pragma unroll
    for (int rr = 0; rr < 4; ++rr) {
        int r = r0 + rr * 16;
        f32x4 v = *(const f32x4*)&K[(size_t)(bi + r) * 1024 + bj + c4];
        v *= 0.03125f;
        half4v h;
        h[0] = (_Float16)v[0]; h[1] = (_Float16)v[1];
        h[2] = (_Float16)v[2]; h[3] = (_Float16)v[3];
        *(half4v*)&w0[(size_t)(bi + r) * 1024 + bj + c4] = h;
        tile[r][c4 + 0] = v[0]; tile[r][c4 + 1] = v[1];
        tile[r][c4 + 2] = v[2]; tile[r][c4 + 3] = v[3];
    }
    __syncthreads();
    const int cT = t >> 4;
    const int rT = (t & 15) * 4;
#pragma unroll
    for (int cc = 0; cc < 4; ++cc) {
        int c = cT + cc * 16;
        half4v h;
        h[0] = (_Float16)tile[rT + 0][c]; h[1] = (_Float16)tile[rT + 1][c];
        h[2] = (_Float16)tile[rT + 2][c]; h[3] = (_Float16)tile[rT + 3][c];
        *(half4v*)&w0T[(size_t)(bj + c) * 1024 + bi + rT] = h;
    }
}

// ---------------------------------------------------------------------------
// small 1024x1024x1024 GEMM:  C[m][n] = sum_k A[m][k] * BT[n][k]
// EPI==0: out = (fp16)acc                         (S_s = w_s^T w_s, via A=BT=wT)
// EPI==1: w_next = 1.5*wcur - (0.5/1024)*acc, also writes transpose
// 64x64 tile, 4 waves (2x2, each 32x32 = 2x2 mfma 16x16x32 f16), BK=64, dbuf.
// ---------------------------------------------------------------------------
template <int EPI>
__global__ __launch_bounds__(256) void gemm1k(const _Float16* __restrict__ A,
                                              const _Float16* __restrict__ BT,
                                              const _Float16* __restrict__ wcur,
                                              _Float16* __restrict__ out,
                                              _Float16* __restrict__ outT) {
    __shared__ _Float16 sA[2][64 * 64];
    __shared__ _Float16 sB[2][64 * 64];
    const int t   = threadIdx.x;
    const int m0  = blockIdx.y * 64, n0 = blockIdx.x * 64;
    const int ln  = t & 63, wv = t >> 6;
    const int wm  = wv >> 1, wn = wv & 1;
    const int q   = ln >> 4, l15 = ln & 15;

    f32x4 acc[2][2];
#pragma unroll
    for (int i = 0; i < 2; ++i)
#pragma unroll
        for (int j = 0; j < 2; ++j) {
            acc[i][j][0] = 0.f; acc[i][j][1] = 0.f;
            acc[i][j][2] = 0.f; acc[i][j][3] = 0.f;
        }

    auto stage = [&](int buf, int k0) {
#pragma unroll
        for (int rnd = 0; rnd < 2; ++rnd) {
            int c = t + rnd * 256;          // chunk id 0..511 (8 chunks/row)
            int row = c >> 3, s = c & 7;
            int gs = s ^ (row & 7);         // XOR swizzle (8x16B granules/row)
            async_copy16(A + (size_t)(m0 + row) * 1024 + k0 + gs * 8, &sA[buf][c * 8]);
            async_copy16(BT + (size_t)(n0 + row) * 1024 + k0 + gs * 8, &sB[buf][c * 8]);
        }
    };

    auto frag = [&](const _Float16* s, int row, int kc) -> half8 {
        return *(const half8*)&s[row * 64 + ((kc ^ (row & 7)) << 3)];
    };

    stage(0, 0);
    int cur = 0;
#pragma unroll 1
    for (int it = 0; it < 16; ++it) {
        __syncthreads();
        if (it < 15) stage(cur ^ 1, (it + 1) * 64);
#pragma unroll
        for (int kk = 0; kk < 2; ++kk) {    // k-sub = kk*32, chunk = kk*4 + q
            half8 a0 = frag(sA[cur], wm * 32 + 0  + l15, kk * 4 + q);
            half8 a1 = frag(sA[cur], wm * 32 + 16 + l15, kk * 4 + q);
            half8 b0 = frag(sB[cur], wn * 32 + 0  + l15, kk * 4 + q);
            half8 b1 = frag(sB[cur], wn * 32 + 16 + l15, kk * 4 + q);
            acc[0][0] = __builtin_amdgcn_mfma_f32_16x16x32_f16(a0, b0, acc[0][0], 0, 0, 0);
            acc[0][1] = __builtin_amdgcn_mfma_f32_16x16x32_f16(a0, b1, acc[0][1], 0, 0, 0);
            acc[1][0] = __builtin_amdgcn_mfma_f32_16x16x32_f16(a1, b0, acc[1][0], 0, 0, 0);
            acc[1][1] = __builtin_amdgcn_mfma_f32_16x16x32_f16(a1, b1, acc[1][1], 0, 0, 0);
        }
        cur ^= 1;
    }

#pragma unroll
    for (int im = 0; im < 2; ++im)
#pragma unroll
        for (int jn = 0; jn < 2; ++jn) {
            int row0 = m0 + wm * 32 + im * 16 + q * 4;
            int col  = n0 + wn * 32 + jn * 16 + l15;
            if (EPI == 0) {
#pragma unroll
                for (int r = 0; r < 4; ++r)
                    out[(size_t)(row0 + r) * 1024 + col] = (_Float16)acc[im][jn][r];
            } else {
                half4v hT;
#pragma unroll
                for (int r = 0; r < 4; ++r) {
                    float w0v = (float)wcur[(size_t)(row0 + r) * 1024 + col];
                    float nv  = 1.5f * w0v - 4.8828125e-4f * acc[im][jn][r];
                    _Float16 h = (_Float16)nv;
                    out[(size_t)(row0 + r) * 1024 + col] = h;
                    hT[r] = h;
                }
                *(half4v*)&outT[(size_t)col * 1024 + row0] = hT;
            }
        }
}

// ---------------------------------------------------------------------------
// big GEMM: Y[32768][1024] = (1/32) * X(f32, cvt->f16) * w_s  + bias
// 128x128 tile, BK=32, 4 waves (2x2, each 64x64 = 4x4 frags), dbuf.
// A staged via VGPR (fp32 load -> cvt -> ds_write, padded rows), B via glds.
// ---------------------------------------------------------------------------
__global__ __launch_bounds__(256) void gemm_big(const float* __restrict__ X,
                                                const _Float16* __restrict__ BT,
                                                const float* __restrict__ bias,
                                                float* __restrict__ Y) {
    __shared__ _Float16 sA[2][128 * 40];   // pad: 40 halves/row
    __shared__ _Float16 sB[2][128 * 32];
    const int t  = threadIdx.x;
    const int m0 = blockIdx.y * 128, n0 = blockIdx.x * 128;
    const int ln = t & 63, wv = t >> 6;
    const int wm = wv >> 1, wn = wv & 1;
    const int q  = ln >> 4, l15 = ln & 15;

    f32x4 acc[4][4];
#pragma unroll
    for (int i = 0; i < 4; ++i)
#pragma unroll
        for (int j = 0; j < 4; ++j) {
            acc[i][j][0] = 0.f; acc[i][j][1] = 0.f;
            acc[i][j][2] = 0.f; acc[i][j][3] = 0.f;
        }

    auto loadA = [&](int k0, f32x4* va) {
#pragma unroll
        for (int rnd = 0; rnd < 4; ++rnd) {
            int c = t + rnd * 256;          // 0..1023 float4-chunks (8/row)
            int row = c >> 3, s4 = c & 7;
            va[rnd] = *(const f32x4*)&X[(size_t)(m0 + row) * 1024 + k0 + s4 * 4];
        }
    };
    auto writeA = [&](int buf, const f32x4* va) {
#pragma unroll
        for (int rnd = 0; rnd < 4; ++rnd) {
            int c = t + rnd * 256;
            int row = c >> 3, s4 = c & 7;
            half4v h;
            h[0] = (_Float16)va[rnd][0]; h[1] = (_Float16)va[rnd][1];
            h[2] = (_Float16)va[rnd][2]; h[3] = (_Float16)va[rnd][3];
            *(half4v*)&sA[buf][row * 40 + s4 * 4] = h;
        }
    };
    auto stageB = [&](int buf, int k0) {
#pragma unroll
        for (int rnd = 0; rnd < 2; ++rnd) {
            int c = t + rnd * 256;          // 0..511 (4 chunks/row)
            int row = c >> 2, s = c & 3;
            int gs = s ^ ((row >> 1) & 3);  // swizzle for 2-way-max reads
            async_copy16(BT + (size_t)(n0 + row) * 1024 + k0 + gs * 8, &sB[buf][c * 8]);
        }
    };

    f32x4 va[4];
    loadA(0, va);
    stageB(0, 0);
    writeA(0, va);
    int cur = 0;
#pragma unroll 1
    for (int it = 0; it < 32; ++it) {
        __syncthreads();
        if (it < 31) {
            loadA((it + 1) * 32, va);       // issue early; consumed after compute
            stageB(cur ^ 1, (it + 1) * 32);
        }
        half8 a[4], b[4];
#pragma unroll
        for (int im = 0; im < 4; ++im) {
            int row = wm * 64 + im * 16 + l15;
            a[im] = *(const half8*)&sA[cur][row * 40 + q * 8];
        }
#pragma unroll
        for (int jn = 0; jn < 4; ++jn) {
            int row = wn * 64 + jn * 16 + l15;
            b[jn] = *(const half8*)&sB[cur][row * 32 + ((q ^ ((row >> 1) & 3)) << 3)];
        }
#pragma unroll
        for (int im = 0; im < 4; ++im)
#pragma unroll
            for (int jn = 0; jn < 4; ++jn)
                acc[im][jn] = __builtin_amdgcn_mfma_f32_16x16x32_f16(a[im], b[jn], acc[im][jn], 0, 0, 0);
        if (it < 31) writeA(cur ^ 1, va);
        cur ^= 1;
    }

#pragma unroll
    for (int jn = 0; jn < 4; ++jn) {
        int col = n0 + wn * 64 + jn * 16 + l15;
        float bv = bias[col];
#pragma unroll
        for (int im = 0; im < 4; ++im) {
            int row0 = m0 + wm * 64 + im * 16 + q * 4;
#pragma unroll
            for (int r = 0; r < 4; ++r)
                Y[(size_t)(row0 + r) * 1024 + col] = acc[im][jn][r] * 0.03125f + bv;
        }
    }
}

// ---------------------------------------------------------------------------
extern "C" void kernel_launch(void* const* d_in, const int* in_sizes, int n_in,
                              void* d_out, int out_size, void* d_ws, size_t ws_size,
                              hipStream_t stream) {
    (void)in_sizes; (void)n_in; (void)out_size; (void)ws_size;
    const float* x    = (const float*)d_in[0];
    const float* kern = (const float*)d_in[1];
    const float* bias = (const float*)d_in[2];
    float* y = (float*)d_out;

    char* ws = (char*)d_ws;
    const size_t SZ = (size_t)1024 * 1024 * sizeof(_Float16);  // 2 MB
    _Float16* wh[2] = {(_Float16*)(ws + 0 * SZ), (_Float16*)(ws + 1 * SZ)};
    _Float16* wT[2] = {(_Float16*)(ws + 2 * SZ), (_Float16*)(ws + 3 * SZ)};
    _Float16* Sh    = (_Float16*)(ws + 4 * SZ);

    prep_w<<<dim3(16, 16), 256, 0, stream>>>(kern, wh[0], wT[0]);

    for (int it = 0; it < 20; ++it) {
        int c = it & 1, n = c ^ 1;
        // S_s = w_s^T w_s : A = BT = wT (both row-slabs of w^T, k contiguous)
        gemm1k<0><<<dim3(16, 16), 256, 0, stream>>>(wT[c], wT[c], nullptr, Sh, nullptr);
        // w_next = 1.5 w - (0.5/1024) * (w_s * S_s); BT = S (symmetric)
        gemm1k<1><<<dim3(16, 16), 256, 0, stream>>>(wh[c], Sh, wh[c], wh[n], wT[n]);
    }
    // final: y = (1/32) x * w_s + bias ; BT = wT (final parity lands in slot 0)
    gemm_big<<<dim3(8, 256), 256, 0, stream>>>(x, wT[0], bias, y);
}